// Round 10
// baseline (421.784 us; speedup 1.0000x reference)
//
#include <hip/hip_runtime.h>
#include <hip/hip_cooperative_groups.h>
#include <math.h>

namespace cg = cooperative_groups;

#define L_SEQ 512
#define BSZ 2
#define NH 8
#define HD 32
#define E 256
#define SCALE 0.17677669529663687f
#define SROW 520                    // slds row stride: worst 2-way bank alias (free, m136)
#define SL_HALF (NH * SROW)         // 4160 floats per l
#define POOL_FLOATS (2 * E + 2 * SL_HALF)   // qs(512) + slds(8320) = 8832 fl = 34.5KB

typedef float f32x4 __attribute__((ext_vector_type(4)));

// ---------------- Phase A: in-projection (unit u: 0..511) ----------------
// unit = (rowgrp rg = u>>2 -> 8 rows, colgrp cgrp = u&3 -> 192 of 768 cols)
__device__ __forceinline__ void phaseA_unit(int u, int t, float (*xs)[E],
    const float* __restrict__ query, const float* __restrict__ Win,
    const float* __restrict__ bin,
    float* __restrict__ q2, float* __restrict__ kh, float* __restrict__ vh)
{
    int rg = u >> 2, cgrp = u & 3;
#pragma unroll
    for (int j = 0; j < 4; ++j) {
        int idx = j * 512 + t;
        int r = idx >> 8, cc = idx & 255;
        xs[r][cc] = query[(size_t)(rg * 8 + r) * E + cc];
    }
    __syncthreads();
    int c = t & 7, cg2 = t >> 3;
#pragma unroll
    for (int pp = 0; pp < 3; ++pp) {
        int col768 = cgrp * 192 + pp * 64 + cg2;
        const f32x4* wp = (const f32x4*)(Win + (size_t)col768 * E);
        float a[8];
#pragma unroll
        for (int r = 0; r < 8; ++r) a[r] = 0.f;
#pragma unroll
        for (int kk = 0; kk < 8; ++kk) {
            f32x4 w = wp[c + kk * 8];
#pragma unroll
            for (int r = 0; r < 8; ++r) {
                f32x4 x = ((const f32x4*)xs[r])[c + kk * 8];
                a[r] += w.x * x.x + w.y * x.y + w.z * x.z + w.w * x.w;
            }
        }
#pragma unroll
        for (int r = 0; r < 8; ++r) {
            a[r] += __shfl_xor(a[r], 1);
            a[r] += __shfl_xor(a[r], 2);
            a[r] += __shfl_xor(a[r], 4);
        }
        if (c == 0) {
            int p = col768 >> 8, col = col768 & 255;
            float bb = bin[col768];
#pragma unroll
            for (int r = 0; r < 8; ++r) {
                int row = rg * 8 + r, l = row >> 1, b = row & 1;
                float val = a[r] + bb;
                if (p == 0) {
                    q2[((size_t)b * L_SEQ + l) * E + col] = val;
                } else {
                    int h = col >> 5, d = col & 31;
                    float* dst = (p == 1) ? kh : vh;
                    dst[((size_t)(b * NH + h) * L_SEQ + l) * HD + d] = val;
                }
            }
        }
    }
    __syncthreads();   // xs reused by next grid-stride unit
}

// ---------------- Phase B: qk + rel + softmax + PV (unit u: 0..511) ----------------
// unit = (b = u>>8, l-pair l0 = (u&255)*2). 8 waves; wave w owns head w.
__device__ __forceinline__ void phaseB_unit(int u, int t, float* pool,
    const float* __restrict__ q2, const float* __restrict__ kh,
    const float* __restrict__ vh, const float* __restrict__ rpe,
    const float* __restrict__ mask,
    float* __restrict__ attn_out, float* __restrict__ oh2)
{
    float* qs   = pool;          // [2][256]
    float* slds = pool + 2 * E;  // [2][SL_HALF]
    int lane = t & 63, wid = t >> 6;
    int b = u >> 8, lp = u & 255, l0 = lp * 2;

    {
        int lsel = t >> 8, cc = t & 255;
        qs[lsel * E + cc] = q2[((size_t)b * L_SEQ + l0 + lsel) * E + cc];
    }
    __syncthreads();

    int cq = lane & 7, h1 = lane >> 3;
    f32x4 qcA = ((const f32x4*)qs)[lane];
    f32x4 qcB = ((const f32x4*)(qs + E))[lane];
    const f32x4* rp = (const f32x4*)(rpe + ((size_t)(b * L_SEQ + l0)) * L_SEQ * E);
    const float* kb_ = kh + (size_t)(b * NH + h1) * L_SEQ * HD;

    // 1024 rows (2 l's x 512 m), interleaved across waves; 1KB contiguous per wave-instr.
#pragma unroll 4
    for (int i = 0; i < 128; ++i) {
        int r = i * 8 + wid;
        int m = r & (L_SEQ - 1);
        f32x4 rv = rp[(size_t)r * 64 + lane];
        f32x4 kv = *(const f32x4*)(kb_ + (size_t)m * HD + cq * 4);
        f32x4 qc = (r & L_SEQ) ? qcB : qcA;
        float part = rv.x * qc.x + rv.y * qc.y + rv.z * qc.z + rv.w * qc.w
                   + SCALE * (kv.x * qc.x + kv.y * qc.y + kv.z * qc.z + kv.w * qc.w);
        part += __shfl_xor(part, 1);
        part += __shfl_xor(part, 2);
        part += __shfl_xor(part, 4);
        if (cq == 0) slds[(r >> 9) * SL_HALF + h1 * SROW + m] = part;
    }
    __syncthreads();

    int h = wid;
#pragma unroll
    for (int lsel = 0; lsel < 2; ++lsel) {
        int l = l0 + lsel;
        const float* mrow = mask + (size_t)l * L_SEQ;
        float sv[8];
        float mx = -1e30f;
#pragma unroll
        for (int i = 0; i < 8; ++i) {
            int m = i * 64 + lane;
            sv[i] = slds[lsel * SL_HALF + h * SROW + m] + mrow[m];
            mx = fmaxf(mx, sv[i]);
        }
#pragma unroll
        for (int off = 32; off > 0; off >>= 1) mx = fmaxf(mx, __shfl_xor(mx, off));
        float sum = 0.f;
#pragma unroll
        for (int i = 0; i < 8; ++i) { sv[i] = __expf(sv[i] - mx); sum += sv[i]; }
#pragma unroll
        for (int off = 32; off > 0; off >>= 1) sum += __shfl_xor(sum, off);
        float inv = 1.0f / sum;
        float* arow = attn_out + ((size_t)(b * NH + h) * L_SEQ + l) * L_SEQ;
#pragma unroll
        for (int i = 0; i < 8; ++i) {
            int m = i * 64 + lane;
            float pn = sv[i] * inv;
            arow[m] = pn;
            slds[lsel * SL_HALF + h * SROW + m] = pn;  // wave-local reuse in PV
        }
    }

    // PV: wave-local; one v pass serves both l's.
    int dq = lane & 7, mg = lane >> 3;
    const f32x4* vbase = (const f32x4*)(vh + (size_t)(b * NH + h) * L_SEQ * HD);
    float ax0 = 0, ay0 = 0, az0 = 0, aw0 = 0;
    float ax1 = 0, ay1 = 0, az1 = 0, aw1 = 0;
#pragma unroll 8
    for (int i = 0; i < 64; ++i) {
        int m = i * 8 + mg;
        f32x4 v4 = vbase[(size_t)m * 8 + dq];
        float p0 = slds[0 * SL_HALF + h * SROW + m];
        float p1 = slds[1 * SL_HALF + h * SROW + m];
        ax0 += p0 * v4.x; ay0 += p0 * v4.y; az0 += p0 * v4.z; aw0 += p0 * v4.w;
        ax1 += p1 * v4.x; ay1 += p1 * v4.y; az1 += p1 * v4.z; aw1 += p1 * v4.w;
    }
#pragma unroll
    for (int off = 8; off <= 32; off <<= 1) {
        ax0 += __shfl_xor(ax0, off); ay0 += __shfl_xor(ay0, off);
        az0 += __shfl_xor(az0, off); aw0 += __shfl_xor(aw0, off);
        ax1 += __shfl_xor(ax1, off); ay1 += __shfl_xor(ay1, off);
        az1 += __shfl_xor(az1, off); aw1 += __shfl_xor(aw1, off);
    }
    if (mg == 0) {
        float4 o0 = {ax0, ay0, az0, aw0};
        float4 o1 = {ax1, ay1, az1, aw1};
        ((float4*)(oh2 + ((size_t)b * L_SEQ + l0) * E))[h * 8 + dq] = o0;
        ((float4*)(oh2 + ((size_t)b * L_SEQ + l0 + 1) * E))[h * 8 + dq] = o1;
    }
    __syncthreads();   // qs/slds reused by next grid-stride unit
}

// ---------------- Phase C: out-projection (unit u: 0..511) ----------------
__device__ __forceinline__ void phaseC_unit(int u, int t, float (*xs)[E],
    const float* __restrict__ oh2, const float* __restrict__ Wout,
    const float* __restrict__ bout, float* __restrict__ out)
{
    int rg = u >> 2, cgrp = u & 3;
#pragma unroll
    for (int j = 0; j < 4; ++j) {
        int idx = j * 512 + t;
        int r = idx >> 8, cc = idx & 255;
        int row = rg * 8 + r, l = row >> 1, b = row & 1;
        xs[r][cc] = oh2[((size_t)b * L_SEQ + l) * E + cc];
    }
    __syncthreads();
    int c = t & 7, cg2 = t >> 3;
    int col = cgrp * 64 + cg2;
    const f32x4* wp = (const f32x4*)(Wout + (size_t)col * E);
    float a[8];
#pragma unroll
    for (int r = 0; r < 8; ++r) a[r] = 0.f;
#pragma unroll
    for (int kk = 0; kk < 8; ++kk) {
        f32x4 w = wp[c + kk * 8];
#pragma unroll
        for (int r = 0; r < 8; ++r) {
            f32x4 x = ((const f32x4*)xs[r])[c + kk * 8];
            a[r] += w.x * x.x + w.y * x.y + w.z * x.z + w.w * x.w;
        }
    }
#pragma unroll
    for (int r = 0; r < 8; ++r) {
        a[r] += __shfl_xor(a[r], 1);
        a[r] += __shfl_xor(a[r], 2);
        a[r] += __shfl_xor(a[r], 4);
    }
    if (c == 0) {
        float bb = bout[col];
#pragma unroll
        for (int r = 0; r < 8; ++r) {
            out[(size_t)(rg * 8 + r) * E + col] = a[r] + bb;
        }
    }
    __syncthreads();
}

// ---------------- Cooperative mega-kernel (grid-stride phases) ----------------
__global__ __launch_bounds__(512, 4)
void fused_coop(const float* __restrict__ query, const float* __restrict__ rpe,
                const float* __restrict__ mask, const float* __restrict__ Win,
                const float* __restrict__ bin, const float* __restrict__ Wout,
                const float* __restrict__ bout,
                float* __restrict__ q2, float* __restrict__ kh,
                float* __restrict__ vh, float* __restrict__ oh2,
                float* __restrict__ out, float* __restrict__ attn_out)
{
    cg::grid_group grid = cg::this_grid();
    __shared__ __align__(16) float pool[POOL_FLOATS];
    int t = threadIdx.x, nb = gridDim.x;
    for (int u = blockIdx.x; u < 512; u += nb)
        phaseA_unit(u, t, (float(*)[E])pool, query, Win, bin, q2, kh, vh);
    grid.sync();
    for (int u = blockIdx.x; u < 512; u += nb)
        phaseB_unit(u, t, pool, q2, kh, vh, rpe, mask, attn_out, oh2);
    grid.sync();
    for (int u = blockIdx.x; u < 512; u += nb)
        phaseC_unit(u, t, (float(*)[E])pool, oh2, Wout, bout, out);
}

// ---------------- Fallback: same phases as 3 plain kernels ----------------
__global__ __launch_bounds__(512, 4)
void kA(const float* __restrict__ query, const float* __restrict__ Win,
        const float* __restrict__ bin, float* __restrict__ q2,
        float* __restrict__ kh, float* __restrict__ vh)
{
    __shared__ __align__(16) float xs[8][E];
    phaseA_unit(blockIdx.x, threadIdx.x, xs, query, Win, bin, q2, kh, vh);
}

__global__ __launch_bounds__(512, 4)
void kB(const float* __restrict__ q2, const float* __restrict__ kh,
        const float* __restrict__ vh, const float* __restrict__ rpe,
        const float* __restrict__ mask, float* __restrict__ attn_out,
        float* __restrict__ oh2)
{
    __shared__ __align__(16) float pool[POOL_FLOATS];
    phaseB_unit(blockIdx.x, threadIdx.x, pool, q2, kh, vh, rpe, mask, attn_out, oh2);
}

__global__ __launch_bounds__(512, 4)
void kC(const float* __restrict__ oh2, const float* __restrict__ Wout,
        const float* __restrict__ bout, float* __restrict__ out)
{
    __shared__ __align__(16) float xs[8][E];
    phaseC_unit(blockIdx.x, threadIdx.x, xs, oh2, Wout, bout, out);
}

extern "C" void kernel_launch(void* const* d_in, const int* in_sizes, int n_in,
                              void* d_out, int out_size, void* d_ws, size_t ws_size,
                              hipStream_t stream) {
    const float* query = (const float*)d_in[0];
    // d_in[1] = key, d_in[2] = value -- UNUSED (reference projects only query)
    const float* rpe   = (const float*)d_in[3];
    const float* mask  = (const float*)d_in[4];
    const float* Win   = (const float*)d_in[5];
    const float* bin   = (const float*)d_in[6];
    const float* Wout  = (const float*)d_in[7];
    const float* bout  = (const float*)d_in[8];

    float* outp = (float*)d_out;                            // (L,B,E)
    float* attn = (float*)d_out + (size_t)L_SEQ * BSZ * E;  // (B*H,L,L)

    float* q2  = (float*)d_ws;                              // (B,L,E)
    float* kh  = q2 + (size_t)BSZ * L_SEQ * E;              // (B*H,L,D)
    float* vh  = kh + (size_t)BSZ * NH * L_SEQ * HD;        // (B*H,L,D)
    float* oh2 = vh + (size_t)BSZ * NH * L_SEQ * HD;        // (B,L,E)

    // Host-only queries (capture-safe): size the coop grid from the runtime.
    int maxB = 0;
    hipError_t eq = hipOccupancyMaxActiveBlocksPerMultiprocessor(
        &maxB, (const void*)fused_coop, 512, 0);
    int dev = 0;
    hipGetDevice(&dev);
    int numCU = 0;
    hipDeviceGetAttribute(&numCU, hipDeviceAttributeMultiprocessorCount, dev);
    long cap = (long)maxB * (long)numCU;

    if (eq == hipSuccess && cap >= 64) {
        int gridn = (int)(cap < 512 ? cap : 512);
        void* args[] = {(void*)&query, (void*)&rpe, (void*)&mask,
                        (void*)&Win, (void*)&bin, (void*)&Wout, (void*)&bout,
                        (void*)&q2, (void*)&kh, (void*)&vh, (void*)&oh2,
                        (void*)&outp, (void*)&attn};
        hipLaunchCooperativeKernel((void*)fused_coop, dim3(gridn), dim3(512),
                                   args, 0, stream);
    } else {
        kA<<<512, 512, 0, stream>>>(query, Win, bin, q2, kh, vh);
        kB<<<512, 512, 0, stream>>>(q2, kh, vh, rpe, mask, attn, oh2);
        kC<<<512, 512, 0, stream>>>(oh2, Wout, bout, outp);
    }
}

// Round 12
// 157.424 us; speedup vs baseline: 2.6793x; 2.6793x over previous
//
#include <hip/hip_runtime.h>
#include <math.h>

#define L_SEQ 512
#define BSZ 2
#define NH 8
#define HD 32
#define E 256
#define SCALE 0.17677669529663687f

typedef float f32x4 __attribute__((ext_vector_type(4)));

// Workspace layouts:
//   q2, k2 : (B, L, E)      -- 1KB contiguous row per (b, seq), same shape as rpe rows
//   vh     : (B*NH, L, HD)  -- head-major, contiguous for PV
//   oh2    : (B, L, E)

// ---------------- Kernel 1: in-projection ----------------
// grid (256 rowgrps, 12 colgrps) -> 3072 blocks (12/CU). Block: 4 rows x 64 cols.
__global__ void inproj_kernel(const float* __restrict__ query,
                              const float* __restrict__ W,
                              const float* __restrict__ bias,
                              float* __restrict__ q2,
                              float* __restrict__ k2,
                              float* __restrict__ vh) {
    int rg = blockIdx.x;             // rows rg*4 .. rg*4+3 (row = l*B + b)
    int cg3 = blockIdx.y;            // out-features cg3*64 .. +63 (of 768)
    int t = threadIdx.x;             // 0..255
    __shared__ float xs[4][E];
#pragma unroll
    for (int r = 0; r < 4; ++r) xs[r][t] = query[(size_t)(rg * 4 + r) * E + t];
    __syncthreads();

    int c = t & 7, cg = t >> 3;
#pragma unroll
    for (int pp = 0; pp < 2; ++pp) {
        int col768 = cg3 * 64 + pp * 32 + cg;
        const float4* wp = (const float4*)(W + (size_t)col768 * E);
        float a0 = 0.f, a1 = 0.f, a2 = 0.f, a3 = 0.f;
#pragma unroll
        for (int kk = 0; kk < 8; ++kk) {
            float4 w  = wp[c + kk * 8];
            float4 x0 = ((const float4*)xs[0])[c + kk * 8];
            float4 x1 = ((const float4*)xs[1])[c + kk * 8];
            float4 x2 = ((const float4*)xs[2])[c + kk * 8];
            float4 x3 = ((const float4*)xs[3])[c + kk * 8];
            a0 += w.x * x0.x + w.y * x0.y + w.z * x0.z + w.w * x0.w;
            a1 += w.x * x1.x + w.y * x1.y + w.z * x1.z + w.w * x1.w;
            a2 += w.x * x2.x + w.y * x2.y + w.z * x2.z + w.w * x2.w;
            a3 += w.x * x3.x + w.y * x3.y + w.z * x3.z + w.w * x3.w;
        }
#pragma unroll
        for (int off = 1; off <= 4; off <<= 1) {
            a0 += __shfl_xor(a0, off);
            a1 += __shfl_xor(a1, off);
            a2 += __shfl_xor(a2, off);
            a3 += __shfl_xor(a3, off);
        }
        if (c == 0) {
            int p = col768 >> 8, col = col768 & 255;
            float bb = bias[col768];
            float res[4] = {a0, a1, a2, a3};
#pragma unroll
            for (int r = 0; r < 4; ++r) {
                int row = rg * 4 + r, l = row >> 1, b = row & 1;
                float val = res[r] + bb;
                if (p == 0) {
                    q2[((size_t)b * L_SEQ + l) * E + col] = val;
                } else if (p == 1) {
                    k2[((size_t)b * L_SEQ + l) * E + col] = val;
                } else {
                    int h = col >> 5, d = col & 31;
                    vh[((size_t)(b * NH + h) * L_SEQ + l) * HD + d] = val;
                }
            }
        }
    }
}

// ---------------- Kernel 2: fused scores + softmax + PV ----------------
// One block per (b, l); all 8 heads. 512 threads = 8 waves; wave w owns head w
// for softmax + PV. Phase 1: each wave-instruction reads one full 1KB rpe row.
// (vs R11: nt load dropped; explicit barrier before PV.)
__global__ void attn_kernel(const float* __restrict__ q2,
                            const float* __restrict__ k2,
                            const float* __restrict__ vh,
                            const float* __restrict__ rpe,
                            const float* __restrict__ mask,
                            float* __restrict__ attn_out,
                            float* __restrict__ oh2) {
    int bid = blockIdx.x;            // b*512 + l
    int b = bid >> 9, l = bid & (L_SEQ - 1);
    int t = threadIdx.x;
    int lane = t & 63, wid = t >> 6;

    __shared__ float qs[E];
    __shared__ float s_lds[NH][L_SEQ + 1];   // pad: conflict-free scatter writes

    if (t < E) qs[t] = q2[((size_t)b * L_SEQ + l) * E + t];
    __syncthreads();

    // ---- Phase 1: scores for all heads. Wave w streams rows m = w*64..w*64+63.
    float4 qc = ((const float4*)qs)[lane];   // lane's head = lane>>3, dims (lane&7)*4..+3
    int h1 = lane >> 3;
    const float* kbase = k2 + (size_t)b * L_SEQ * E;
    const float* rbase = rpe + ((size_t)(b * L_SEQ + l)) * L_SEQ * E;

#pragma unroll 4
    for (int i = 0; i < 64; ++i) {
        int m = wid * 64 + i;
        float4 kv = ((const float4*)(kbase + (size_t)m * E))[lane];
        f32x4 rv = *(((const f32x4*)(rbase + (size_t)m * E)) + lane);
        float part = (kv.x * qc.x + kv.y * qc.y + kv.z * qc.z + kv.w * qc.w) * SCALE
                   +  rv.x * qc.x + rv.y * qc.y + rv.z * qc.z + rv.w * qc.w;
        part += __shfl_xor(part, 1);
        part += __shfl_xor(part, 2);
        part += __shfl_xor(part, 4);
        if ((lane & 7) == 0) s_lds[h1][m] = part;
    }
    __syncthreads();

    // ---- Phase 2: softmax. Wave w owns head w (512 scores = 64 lanes x 8).
    int h = wid;
    const float* mrow = mask + (size_t)l * L_SEQ;
    float sv[8];
    float mx = -1e30f;
#pragma unroll
    for (int i = 0; i < 8; ++i) {
        int m = i * 64 + lane;
        sv[i] = s_lds[h][m] + mrow[m];
        mx = fmaxf(mx, sv[i]);
    }
#pragma unroll
    for (int off = 32; off > 0; off >>= 1) mx = fmaxf(mx, __shfl_xor(mx, off));
    float sum = 0.f;
#pragma unroll
    for (int i = 0; i < 8; ++i) { sv[i] = __expf(sv[i] - mx); sum += sv[i]; }
#pragma unroll
    for (int off = 32; off > 0; off >>= 1) sum += __shfl_xor(sum, off);
    float inv = 1.0f / sum;

    float* arow = attn_out + ((size_t)(b * NH + h) * L_SEQ + l) * L_SEQ;
#pragma unroll
    for (int i = 0; i < 8; ++i) {
        int m = i * 64 + lane;
        float pn = sv[i] * inv;
        arow[m] = pn;
        s_lds[h][m] = pn;
    }
    __syncthreads();   // hard fence before PV reads the prob rows

    // ---- Phase 3: PV for head h.
    int dq = lane & 7, mg = lane >> 3;
    const f32x4* vbase = (const f32x4*)(vh + (size_t)(b * NH + h) * L_SEQ * HD);
    float4 acc = {0.f, 0.f, 0.f, 0.f};
#pragma unroll 4
    for (int i = 0; i < 64; ++i) {
        int m = i * 8 + mg;
        f32x4 v4 = vbase[(size_t)m * 8 + dq];
        float p = s_lds[h][m];
        acc.x += p * v4.x; acc.y += p * v4.y; acc.z += p * v4.z; acc.w += p * v4.w;
    }
#pragma unroll
    for (int off = 8; off <= 32; off <<= 1) {
        acc.x += __shfl_xor(acc.x, off);
        acc.y += __shfl_xor(acc.y, off);
        acc.z += __shfl_xor(acc.z, off);
        acc.w += __shfl_xor(acc.w, off);
    }
    if (mg == 0) {
        ((float4*)(oh2 + ((size_t)b * L_SEQ + l) * E))[h * 8 + dq] = acc;
    }
}

// ---------------- Kernel 3: out-projection ----------------
// grid (256 rowgrps, 4 colgrps) -> 1024 blocks. Block: 4 rows x 64 cols.
__global__ void outproj_kernel(const float* __restrict__ oh2,
                               const float* __restrict__ W,
                               const float* __restrict__ bias,
                               float* __restrict__ out) {
    int rg = blockIdx.x;
    int cg3 = blockIdx.y;            // cols cg3*64 .. +63
    int t = threadIdx.x;
    __shared__ float xs[4][E];
#pragma unroll
    for (int r = 0; r < 4; ++r) {
        int row = rg * 4 + r, l = row >> 1, b = row & 1;
        xs[r][t] = oh2[((size_t)b * L_SEQ + l) * E + t];
    }
    __syncthreads();

    int c = t & 7, cg = t >> 3;
#pragma unroll
    for (int pp = 0; pp < 2; ++pp) {
        int col = cg3 * 64 + pp * 32 + cg;
        const float4* wp = (const float4*)(W + (size_t)col * E);
        float a0 = 0.f, a1 = 0.f, a2 = 0.f, a3 = 0.f;
#pragma unroll
        for (int kk = 0; kk < 8; ++kk) {
            float4 w  = wp[c + kk * 8];
            float4 x0 = ((const float4*)xs[0])[c + kk * 8];
            float4 x1 = ((const float4*)xs[1])[c + kk * 8];
            float4 x2 = ((const float4*)xs[2])[c + kk * 8];
            float4 x3 = ((const float4*)xs[3])[c + kk * 8];
            a0 += w.x * x0.x + w.y * x0.y + w.z * x0.z + w.w * x0.w;
            a1 += w.x * x1.x + w.y * x1.y + w.z * x1.z + w.w * x1.w;
            a2 += w.x * x2.x + w.y * x2.y + w.z * x2.z + w.w * x2.w;
            a3 += w.x * x3.x + w.y * x3.y + w.z * x3.z + w.w * x3.w;
        }
#pragma unroll
        for (int off = 1; off <= 4; off <<= 1) {
            a0 += __shfl_xor(a0, off);
            a1 += __shfl_xor(a1, off);
            a2 += __shfl_xor(a2, off);
            a3 += __shfl_xor(a3, off);
        }
        if (c == 0) {
            float bb = bias[col];
            float res[4] = {a0, a1, a2, a3};
#pragma unroll
            for (int r = 0; r < 4; ++r) {
                out[(size_t)(rg * 4 + r) * E + col] = res[r] + bb;
            }
        }
    }
}

extern "C" void kernel_launch(void* const* d_in, const int* in_sizes, int n_in,
                              void* d_out, int out_size, void* d_ws, size_t ws_size,
                              hipStream_t stream) {
    const float* query = (const float*)d_in[0];
    // d_in[1] = key, d_in[2] = value -- UNUSED (reference projects only query)
    const float* rpe   = (const float*)d_in[3];
    const float* mask  = (const float*)d_in[4];
    const float* Win   = (const float*)d_in[5];
    const float* bin   = (const float*)d_in[6];
    const float* Wout  = (const float*)d_in[7];
    const float* bout  = (const float*)d_in[8];

    float* out  = (float*)d_out;                            // (L,B,E)
    float* attn = (float*)d_out + (size_t)L_SEQ * BSZ * E;  // (B*H,L,L)

    float* q2  = (float*)d_ws;                              // (B,L,E)
    float* k2  = q2 + (size_t)BSZ * L_SEQ * E;              // (B,L,E)
    float* vh  = k2 + (size_t)BSZ * L_SEQ * E;              // (B*H,L,D)
    float* oh2 = vh + (size_t)BSZ * NH * L_SEQ * HD;        // (B,L,E)

    inproj_kernel<<<dim3(256, 12), 256, 0, stream>>>(query, Win, bin, q2, k2, vh);
    attn_kernel<<<BSZ * L_SEQ, 512, 0, stream>>>(q2, k2, vh, rpe, mask, attn, oh2);
    outproj_kernel<<<dim3(256, 4), 256, 0, stream>>>(oh2, Wout, bout, out);
}